// Round 3
// baseline (749.457 us; speedup 1.0000x reference)
//
#include <hip/hip_runtime.h>
#include <math.h>

// Problem constants
#define NB    2048
#define KK    64
#define MM    64
#define DD    256
#define NITER 15
#define MITER 3
#define IEPS  20.0f   // 1/0.05

#define NBLK  512     // persistent blocks for mlp_cdist
#define BPB   4       // batches per block

typedef __bf16 bf16_t;
typedef bf16_t bf16x8 __attribute__((ext_vector_type(8)));
typedef bf16_t bf16x4 __attribute__((ext_vector_type(4)));
typedef float  f32x16 __attribute__((ext_vector_type(16)));

#define CSTR 65    // f32 elems per LDS C/T row (64 + 1 pad)

// W workspace layout (fragment-native):
//   wf[layer*65536 + ((eb*16 + kc)*64 + lane)*8 + u]
//   = W[eb*32 + (lane&31)][kc*16 + (lane>>5)*8 + u]

__global__ __launch_bounds__(256) void convert_w_frag(const float* __restrict__ W1,
                                                      const float* __restrict__ W2,
                                                      bf16_t* __restrict__ wf) {
    const int j19 = blockIdx.x * 256 + threadIdx.x;   // grid 512 -> 131072
    const int layer = j19 >> 16;
    const int j = j19 & 65535;
    const int u    = j & 7;
    const int lane = (j >> 3) & 63;
    const int kc   = (j >> 9) & 15;
    const int eb   = j >> 13;
    const int l31  = lane & 31;
    const int lh   = lane >> 5;
    const int src  = (eb * 32 + l31) * 256 + kc * 16 + lh * 8 + u;
    wf[j19] = (bf16_t)(layer ? W2[src] : W1[src]);
}

// ---------------------------------------------------------------------------
// Kernel A: persistent blocks, 4 batches each, cross-batch register prefetch.
// Xs layout: row r (0..127) of 256 bf16 = 32 chunks of 8 elems (16B).
// Chunk swizzle: phys_chunk = log_chunk ^ (r & 7)  -> conflict-free ds_read_b128.
// Row norms fused into layer-2 epilogue (shfl + LDS atomicAdd).
// ---------------------------------------------------------------------------
__global__ __launch_bounds__(512, 4) void mlp_cdist(
    const float* __restrict__ sq, const float* __restrict__ sr,
    const float* __restrict__ b1, const float* __restrict__ b2,
    const bf16_t* __restrict__ wf,
    float* __restrict__ out) {

    __shared__ __align__(16) bf16_t Xs[128 * 256];   // 64 KB
    __shared__ float nrm[128];
    __shared__ float b1_s[256], b2_s[256];

    const int t   = threadIdx.x;
    const int ln  = t & 63;
    const int wv  = t >> 6;          // 0..7
    const int l31 = ln & 31;
    const int lh  = ln >> 5;
    const int sw  = l31 & 7;         // row-swizzle key for all MFMA-pattern rows

    if (t < 256) b1_s[t] = b1[t];
    else         b2_s[t - 256] = b2[t - 256];

    int b = blockIdx.x;

    // ---- prologue: load batch b into prefetch regs ----
    float4 pf0[8], pf1[8];
    {
        const float4* sq4 = (const float4*)(sq + (size_t)b * 16384);
        const float4* sr4 = (const float4*)(sr + (size_t)b * 16384);
        #pragma unroll
        for (int i = 0; i < 8; ++i) pf0[i] = sq4[(wv + i * 8) * 64 + ln];
        #pragma unroll
        for (int i = 0; i < 8; ++i) pf1[i] = sr4[(wv + i * 8) * 64 + ln];
    }

    for (int it = 0; it < BPB; ++it, b += NBLK) {
        // ---- stage: regs -> Xs (bf16, swizzled); zero nrm ----
        {
            const int cw = (((ln >> 1) ^ wv) << 3) + (ln & 1) * 4;  // (r&7)==wv
            #pragma unroll
            for (int i = 0; i < 8; ++i) {
                const int r = wv + i * 8;
                bf16x4 p;
                p[0] = (bf16_t)pf0[i].x; p[1] = (bf16_t)pf0[i].y;
                p[2] = (bf16_t)pf0[i].z; p[3] = (bf16_t)pf0[i].w;
                *(bf16x4*)&Xs[r * 256 + cw] = p;
                bf16x4 q;
                q[0] = (bf16_t)pf1[i].x; q[1] = (bf16_t)pf1[i].y;
                q[2] = (bf16_t)pf1[i].z; q[3] = (bf16_t)pf1[i].w;
                *(bf16x4*)&Xs[(64 + r) * 256 + cw] = q;
            }
            if (t < 128) nrm[t] = 0.0f;
        }
        __syncthreads();

        // ---- issue prefetch of next batch's sq-half (in flight during MFMA) ----
        if (it < BPB - 1) {
            const float4* nq4 = (const float4*)(sq + (size_t)(b + NBLK) * 16384);
            #pragma unroll
            for (int i = 0; i < 8; ++i) pf0[i] = nq4[(wv + i * 8) * 64 + ln];
        }

        // ---- Phase 1: layer 1 (half-split: acc = 32 AGPR) ----
        bf16x4 hreg[2][2][4];   // [half][z][g]
        #pragma unroll
        for (int half = 0; half < 2; ++half) {
            f32x16 acc0, acc1;
            #pragma unroll
            for (int i = 0; i < 16; ++i) { acc0[i] = 0.0f; acc1[i] = 0.0f; }
            const bf16_t* xrow0 = Xs + (half * 64 + l31) * 256;
            const bf16_t* xrow1 = xrow0 + 32 * 256;
            #pragma unroll
            for (int kg = 0; kg < 4; ++kg) {
                const bf16_t* wbase = wf + ((size_t)wv * 16 + kg * 4) * 512 + ln * 8;
                bf16x8 af[4];
                #pragma unroll
                for (int u = 0; u < 4; ++u)
                    af[u] = *(const bf16x8*)(wbase + u * 512);
                #pragma unroll
                for (int u = 0; u < 4; ++u) {
                    const int ch = ((2 * (kg * 4 + u) + lh) ^ sw) << 3;
                    bf16x8 bx0 = *(const bf16x8*)(xrow0 + ch);
                    bf16x8 bx1 = *(const bf16x8*)(xrow1 + ch);
                    acc0 = __builtin_amdgcn_mfma_f32_32x32x16_bf16(af[u], bx0, acc0, 0, 0, 0);
                    acc1 = __builtin_amdgcn_mfma_f32_32x32x16_bf16(af[u], bx1, acc1, 0, 0, 0);
                }
            }
            const int e0 = wv * 32;
            #pragma unroll
            for (int g = 0; g < 4; ++g) {
                const int e = e0 + 8 * g + 4 * lh;
                #pragma unroll
                for (int rr = 0; rr < 4; ++rr) {
                    hreg[half][0][g][rr] = (bf16_t)fmaxf(acc0[4 * g + rr] + b1_s[e + rr], 0.0f);
                    hreg[half][1][g][rr] = (bf16_t)fmaxf(acc1[4 * g + rr] + b1_s[e + rr], 0.0f);
                }
            }
        }
        __syncthreads();             // all waves done reading X

        // ---- write H over Xs (swizzled) ----
        #pragma unroll
        for (int half = 0; half < 2; ++half)
            #pragma unroll
            for (int z = 0; z < 2; ++z) {
                const int n = half * 64 + z * 32 + l31;     // n&7 == sw
                #pragma unroll
                for (int g = 0; g < 4; ++g) {
                    const int cc = (((wv * 4 + g) ^ sw) << 3) + 4 * lh;
                    *(bf16x4*)&Xs[n * 256 + cc] = hreg[half][z][g];
                }
            }
        __syncthreads();

        // ---- Phase 2: layer 2 (+ fused row norms) ----
        {
            float ps[2][2] = {{0.0f, 0.0f}, {0.0f, 0.0f}};
            #pragma unroll
            for (int half = 0; half < 2; ++half) {
                f32x16 acc0, acc1;
                #pragma unroll
                for (int i = 0; i < 16; ++i) { acc0[i] = 0.0f; acc1[i] = 0.0f; }
                const bf16_t* xrow0 = Xs + (half * 64 + l31) * 256;
                const bf16_t* xrow1 = xrow0 + 32 * 256;
                #pragma unroll
                for (int kg = 0; kg < 4; ++kg) {
                    const bf16_t* wbase = wf + 65536 + ((size_t)wv * 16 + kg * 4) * 512 + ln * 8;
                    bf16x8 af[4];
                    #pragma unroll
                    for (int u = 0; u < 4; ++u)
                        af[u] = *(const bf16x8*)(wbase + u * 512);
                    #pragma unroll
                    for (int u = 0; u < 4; ++u) {
                        const int ch = ((2 * (kg * 4 + u) + lh) ^ sw) << 3;
                        bf16x8 bx0 = *(const bf16x8*)(xrow0 + ch);
                        bf16x8 bx1 = *(const bf16x8*)(xrow1 + ch);
                        acc0 = __builtin_amdgcn_mfma_f32_32x32x16_bf16(af[u], bx0, acc0, 0, 0, 0);
                        acc1 = __builtin_amdgcn_mfma_f32_32x32x16_bf16(af[u], bx1, acc1, 0, 0, 0);
                    }
                }
                const int e0 = wv * 32;
                #pragma unroll
                for (int g = 0; g < 4; ++g) {
                    const int e = e0 + 8 * g + 4 * lh;
                    #pragma unroll
                    for (int rr = 0; rr < 4; ++rr) {
                        bf16_t v0 = (bf16_t)(acc0[4 * g + rr] + b2_s[e + rr]);
                        bf16_t v1 = (bf16_t)(acc1[4 * g + rr] + b2_s[e + rr]);
                        hreg[half][0][g][rr] = v0;
                        hreg[half][1][g][rr] = v1;
                        float f0 = (float)v0, f1 = (float)v1;
                        ps[half][0] = fmaf(f0, f0, ps[half][0]);
                        ps[half][1] = fmaf(f1, f1, ps[half][1]);
                    }
                }
            }
            // fold lh halves (lanes l <-> l+32 share l31) and publish norms
            #pragma unroll
            for (int half = 0; half < 2; ++half)
                #pragma unroll
                for (int z = 0; z < 2; ++z) {
                    float s = ps[half][z];
                    s += __shfl_xor(s, 32);
                    if (lh == 0) atomicAdd(&nrm[half * 64 + z * 32 + l31], s);
                }
        }
        __syncthreads();             // all waves done reading H

        // ---- write f over Xs (swizzled) ----
        #pragma unroll
        for (int half = 0; half < 2; ++half)
            #pragma unroll
            for (int z = 0; z < 2; ++z) {
                const int n = half * 64 + z * 32 + l31;
                #pragma unroll
                for (int g = 0; g < 4; ++g) {
                    const int cc = (((wv * 4 + g) ^ sw) << 3) + 4 * lh;
                    *(bf16x4*)&Xs[n * 256 + cc] = hreg[half][z][g];
                }
            }

        // ---- issue prefetch of next batch's sr-half ----
        if (it < BPB - 1) {
            const float4* nr4 = (const float4*)(sr + (size_t)(b + NBLK) * 16384);
            #pragma unroll
            for (int i = 0; i < 8; ++i) pf1[i] = nr4[(wv + i * 8) * 64 + ln];
        }
        __syncthreads();             // f + nrm ready

        // ---- cdist (waves 0..3), C -> global ----
        if (wv < 4) {
            const int qt = wv >> 1, rt = wv & 1;
            const bf16_t* qa = Xs + (qt * 32 + l31) * 256;
            const bf16_t* ra = Xs + (64 + rt * 32 + l31) * 256;
            f32x16 acc;
            #pragma unroll
            for (int i = 0; i < 16; ++i) acc[i] = 0.0f;
            #pragma unroll
            for (int kc = 0; kc < 16; ++kc) {
                const int ch = ((2 * kc + lh) ^ sw) << 3;
                bf16x8 av = *(const bf16x8*)(qa + ch);
                bf16x8 bv = *(const bf16x8*)(ra + ch);
                acc = __builtin_amdgcn_mfma_f32_32x32x16_bf16(av, bv, acc, 0, 0, 0);
            }
            const int mcol  = rt * 32 + l31;
            const int qbase = qt * 32;
            const float nr_m = nrm[64 + mcol];
            float* outC = out + 2048 + (size_t)2048 * 4096 + (size_t)b * 4096;
            #pragma unroll
            for (int g = 0; g < 4; ++g) {
                #pragma unroll
                for (int rr = 0; rr < 4; ++rr) {
                    const int q = qbase + 8 * g + 4 * lh + rr;
                    float d2 = nrm[q] + nr_m - 2.0f * acc[4 * g + rr];
                    outC[q * 64 + mcol] = sqrtf(fmaxf(d2, 0.0f));
                }
            }
        }
        __syncthreads();             // f dead everywhere; safe to restage
    }
}

// ---------------------------------------------------------------------------
// Kernel B: Sinkhorn + power iterations + outputs, from C in global.
// LDS 34.3 KB -> 4 blocks/CU; __launch_bounds__(512,8) caps VGPR at 64.
// ---------------------------------------------------------------------------
__global__ __launch_bounds__(512, 8) void sinkhorn_from_C(
    const float* __restrict__ mq, const float* __restrict__ mr,
    float* __restrict__ out) {

    __shared__ float Cs[64 * CSTR];
    __shared__ float Ts[64 * CSTR];
    __shared__ float lmq_s[64], lmr_s[64], la_s[64], lb_s[64];
    __shared__ float red_s[8];

    const int b  = blockIdx.x;
    const int t  = threadIdx.x;
    const int ln = t & 63;
    const int wv = t >> 6;
    const int ki = t >> 3;      // 0..63 (row)
    const int jj = t & 7;       // strip of 8 cols

    // ---- stage C (each thread owns row ki, cols jj*8..jj*8+7) ----
    const float* Cg = out + 2048 + (size_t)2048 * 4096 + (size_t)b * 4096 + ki * 64 + jj * 8;
    const float4 c0 = ((const float4*)Cg)[0];
    const float4 c1 = ((const float4*)Cg)[1];

    if (t < 64)        lmq_s[t]       = __logf(fmaxf(mq[(size_t)b * 64 + t], 1e-8f));
    else if (t < 128)  lmr_s[t - 64]  = __logf(fmaxf(mr[(size_t)b * 64 + (t - 64)], 1e-8f));
    else if (t < 192)  lb_s[t - 128]  = 0.0f;

    {
        float* cr = &Cs[ki * CSTR + jj * 8];
        cr[0] = c0.x; cr[1] = c0.y; cr[2] = c0.z; cr[3] = c0.w;
        cr[4] = c1.x; cr[5] = c1.y; cr[6] = c1.z; cr[7] = c1.w;
    }
    __syncthreads();

    // ---- Sinkhorn init: rowV from regs, colV via LDS transpose ----
    float rowV[8], colV[8];
    {
        const float cv[8] = {c0.x, c0.y, c0.z, c0.w, c1.x, c1.y, c1.z, c1.w};
        #pragma unroll
        for (int i = 0; i < 8; ++i)
            rowV[i] = fmaf(cv[i], -IEPS, lmr_s[jj * 8 + i]);
        #pragma unroll
        for (int i = 0; i < 8; ++i)
            colV[i] = fmaf(Cs[(jj * 8 + i) * CSTR + ki], -IEPS, lmq_s[jj * 8 + i]);
    }
    const float lmq_k = lmq_s[ki];
    const float lmr_m = lmr_s[ki];

    for (int it = 0; it < NITER; ++it) {
        float mx = -1e30f;
        #pragma unroll
        for (int i = 0; i < 8; ++i) mx = fmaxf(mx, rowV[i] + lb_s[jj * 8 + i]);
        mx = fmaxf(mx, __shfl_xor(mx, 1));
        mx = fmaxf(mx, __shfl_xor(mx, 2));
        mx = fmaxf(mx, __shfl_xor(mx, 4));
        float s = 0.0f;
        #pragma unroll
        for (int i = 0; i < 8; ++i) s += __expf(rowV[i] + lb_s[jj * 8 + i] - mx);
        s += __shfl_xor(s, 1);
        s += __shfl_xor(s, 2);
        s += __shfl_xor(s, 4);
        if (jj == 0) la_s[ki] = -(lmq_k + mx + __logf(s));
        __syncthreads();

        mx = -1e30f;
        #pragma unroll
        for (int i = 0; i < 8; ++i) mx = fmaxf(mx, colV[i] + la_s[jj * 8 + i]);
        mx = fmaxf(mx, __shfl_xor(mx, 1));
        mx = fmaxf(mx, __shfl_xor(mx, 2));
        mx = fmaxf(mx, __shfl_xor(mx, 4));
        float s2 = 0.0f;
        #pragma unroll
        for (int i = 0; i < 8; ++i) s2 += __expf(colV[i] + la_s[jj * 8 + i] - mx);
        s2 += __shfl_xor(s2, 1);
        s2 += __shfl_xor(s2, 2);
        s2 += __shfl_xor(s2, 4);
        if (jj == 0) lb_s[ki] = -(lmr_m + mx + __logf(s2));
        __syncthreads();
    }

    // ---- T = exp(lK + la + lb) ----
    {
        const float base = lmq_k + la_s[ki];
        #pragma unroll
        for (int i = 0; i < 8; ++i) {
            const int m2 = jj * 8 + i;
            Ts[ki * CSTR + m2] = __expf(rowV[i] + lb_s[m2] + base);
        }
    }
    __syncthreads();

    // ---- power iterations ----
    for (int pi = 0; pi < MITER; ++pi) {
        float vv[8], rs = 0.0f;
        #pragma unroll
        for (int i = 0; i < 8; ++i) {
            float v = Ts[ki * CSTR + jj * 8 + i];
            v = v * v; vv[i] = v; rs += v;
        }
        rs += __shfl_xor(rs, 1); rs += __shfl_xor(rs, 2); rs += __shfl_xor(rs, 4);
        float inv = 1.0f / (rs + 1e-8f);
        #pragma unroll
        for (int i = 0; i < 8; ++i) Ts[ki * CSTR + jj * 8 + i] = vv[i] * inv;
        __syncthreads();

        float cs = 0.0f;
        #pragma unroll
        for (int i = 0; i < 8; ++i) { float v = Ts[(jj * 8 + i) * CSTR + ki]; vv[i] = v; cs += v; }
        cs += __shfl_xor(cs, 1); cs += __shfl_xor(cs, 2); cs += __shfl_xor(cs, 4);
        inv = 1.0f / (cs + 1e-8f);
        #pragma unroll
        for (int i = 0; i < 8; ++i) Ts[(jj * 8 + i) * CSTR + ki] = vv[i] * inv;
        __syncthreads();
    }

    // ---- write T, c = sum(T*C), sigmoid(-c) ----
    {
        float part = 0.0f;
        float tq[8];
        #pragma unroll
        for (int i = 0; i < 8; ++i) {
            const int m2 = jj * 8 + i;
            float tv = Ts[ki * CSTR + m2];
            tq[i] = tv;
            part = fmaf(tv, Cs[ki * CSTR + m2], part);
        }
        float* outT = out + 2048 + (size_t)b * 4096 + ki * 64 + jj * 8;
        ((float4*)outT)[0] = make_float4(tq[0], tq[1], tq[2], tq[3]);
        ((float4*)outT)[1] = make_float4(tq[4], tq[5], tq[6], tq[7]);
        #pragma unroll
        for (int off = 1; off < 64; off <<= 1) part += __shfl_xor(part, off);
        if (ln == 0) red_s[wv] = part;
    }
    __syncthreads();
    if (t == 0) {
        float c = 0.0f;
        #pragma unroll
        for (int w = 0; w < 8; ++w) c += red_s[w];
        out[2048 + (size_t)2 * 2048 * 4096 + b] = c;
        out[b] = 1.0f / (1.0f + __expf(c));
    }
}

extern "C" void kernel_launch(void* const* d_in, const int* in_sizes, int n_in,
                              void* d_out, int out_size, void* d_ws, size_t ws_size,
                              hipStream_t stream) {
    const float* sq = (const float*)d_in[0];
    const float* sr = (const float*)d_in[1];
    const float* mq = (const float*)d_in[2];
    const float* mr = (const float*)d_in[3];
    const float* W1 = (const float*)d_in[4];
    const float* b1 = (const float*)d_in[5];
    const float* W2 = (const float*)d_in[6];
    const float* b2 = (const float*)d_in[7];

    bf16_t* wf = (bf16_t*)d_ws;   // 131072 bf16 = 256 KB

    convert_w_frag<<<512, 256, 0, stream>>>(W1, W2, wf);
    mlp_cdist<<<NBLK, 512, 0, stream>>>(sq, sr, b1, b2, wf, (float*)d_out);
    sinkhorn_from_C<<<NB, 512, 0, stream>>>(mq, mr, (float*)d_out);
}

// Round 4
// 427.251 us; speedup vs baseline: 1.7541x; 1.7541x over previous
//
#include <hip/hip_runtime.h>
#include <math.h>

// Problem constants
#define NB    2048
#define KK    64
#define MM    64
#define DD    256
#define NITER 15
#define MITER 3
#define IEPS  20.0f   // 1/0.05

typedef __bf16 bf16_t;
typedef bf16_t bf16x8 __attribute__((ext_vector_type(8)));
typedef bf16_t bf16x4 __attribute__((ext_vector_type(4)));
typedef float  f32x16 __attribute__((ext_vector_type(16)));

#define XSTR 264   // bf16 elems per LDS activation row (256 + 8 pad)

// W workspace layout (fragment-native):
//   wf[layer*65536 + ((eb*16 + kc)*64 + lane)*8 + u]
//   = W[eb*32 + (lane&31)][kc*16 + (lane>>5)*8 + u]

__global__ __launch_bounds__(256) void convert_w_frag(const float* __restrict__ W1,
                                                      const float* __restrict__ W2,
                                                      bf16_t* __restrict__ wf) {
    const int j19 = blockIdx.x * 256 + threadIdx.x;   // grid 512 -> 131072
    const int layer = j19 >> 16;
    const int j = j19 & 65535;
    const int u    = j & 7;
    const int lane = (j >> 3) & 63;
    const int kc   = (j >> 9) & 15;
    const int eb   = j >> 13;
    const int l31  = lane & 31;
    const int lh   = lane >> 5;
    const int src  = (eb * 32 + l31) * 256 + kc * 16 + lh * 8 + u;
    wf[j19] = (bf16_t)(layer ? W2[src] : W1[src]);
}

// ---------------------------------------------------------------------------
// Kernel A: MLP (2 layers) + cdist, writes C to global. One batch per block,
// 512 threads (8 waves). Wave wv owns feature slice [wv*32, wv*32+32).
// (Byte-identical to the round-2 version measured at 148 us. Register budget
//  is exactly 64 VGPR + 64 AGPR = 128 at 4 waves/SIMD -- NO cross-phase
//  register prefetch fits; round-3's attempt spilled to scratch, 3.2x slower.)
// ---------------------------------------------------------------------------
__global__ __launch_bounds__(512, 4) void mlp_cdist(
    const float* __restrict__ sq, const float* __restrict__ sr,
    const float* __restrict__ b1, const float* __restrict__ b2,
    const bf16_t* __restrict__ wf,
    float* __restrict__ out) {

    __shared__ __align__(16) char smem[128 * XSTR * 2];   // 67584 B
    bf16_t* Xs = (bf16_t*)smem;
    __shared__ float nrm[128];
    __shared__ float b1_s[256], b2_s[256];

    const int b  = blockIdx.x;
    const int t  = threadIdx.x;
    const int ln = t & 63;
    const int wv = t >> 6;          // 0..7
    const int l31 = ln & 31;
    const int lh  = ln >> 5;

    // ---- Phase 0: stage X = [sq_b ; sr_b] fp32 -> bf16 ----
    {
        const float4* sq4 = (const float4*)(sq + (size_t)b * 64 * 256);
        const float4* sr4 = (const float4*)(sr + (size_t)b * 64 * 256);
        float4 xr[16];
        #pragma unroll
        for (int it = 0; it < 16; ++it) {
            const int r = wv + it * 8;          // wave-uniform row 0..127
            xr[it] = (r < 64) ? sq4[r * 64 + ln] : sr4[(r - 64) * 64 + ln];
        }
        #pragma unroll
        for (int it = 0; it < 16; ++it) {
            const int r = wv + it * 8;
            bf16x4 p;
            p[0] = (bf16_t)xr[it].x; p[1] = (bf16_t)xr[it].y;
            p[2] = (bf16_t)xr[it].z; p[3] = (bf16_t)xr[it].w;
            *(bf16x4*)&Xs[(size_t)r * XSTR + ln * 4] = p;
        }
        if (t < 256) b1_s[t] = b1[t];
        else         b2_s[t - 256] = b2[t - 256];
    }
    __syncthreads();

    // ---- Phase 1: layer 1, H -> hreg ----
    bf16x4 hreg[2][2][4];   // [half][z][g]
    {
        const bf16_t* wbase = wf + ((size_t)wv * 16) * 512 + ln * 8;
        f32x16 acc[2][2];
        #pragma unroll
        for (int i = 0; i < 16; ++i) {
            acc[0][0][i] = 0.0f; acc[0][1][i] = 0.0f;
            acc[1][0][i] = 0.0f; acc[1][1][i] = 0.0f;
        }
        #pragma unroll
        for (int kg = 0; kg < 2; ++kg) {
            bf16x8 af[8];
            #pragma unroll
            for (int u = 0; u < 8; ++u)
                af[u] = *(const bf16x8*)(wbase + (size_t)(kg * 8 + u) * 512);
            #pragma unroll
            for (int half = 0; half < 2; ++half) {
                const bf16_t* x0 = Xs + (size_t)(half * 64 + l31) * XSTR + lh * 8;
                const bf16_t* x1 = x0 + 32 * XSTR;
                #pragma unroll
                for (int u = 0; u < 8; ++u) {
                    const int kc = kg * 8 + u;
                    bf16x8 bx0 = *(const bf16x8*)(x0 + kc * 16);
                    bf16x8 bx1 = *(const bf16x8*)(x1 + kc * 16);
                    acc[half][0] = __builtin_amdgcn_mfma_f32_32x32x16_bf16(af[u], bx0, acc[half][0], 0, 0, 0);
                    acc[half][1] = __builtin_amdgcn_mfma_f32_32x32x16_bf16(af[u], bx1, acc[half][1], 0, 0, 0);
                }
            }
        }
        const int e0 = wv * 32;
        #pragma unroll
        for (int half = 0; half < 2; ++half)
            #pragma unroll
            for (int z = 0; z < 2; ++z)
                #pragma unroll
                for (int g = 0; g < 4; ++g) {
                    const int e = e0 + 8 * g + 4 * lh;
                    #pragma unroll
                    for (int rr = 0; rr < 4; ++rr) {
                        float v = acc[half][z][4 * g + rr] + b1_s[e + rr];
                        hreg[half][z][g][rr] = (bf16_t)fmaxf(v, 0.0f);
                    }
                }
    }
    __syncthreads();             // all waves done reading X

    // ---- write H over Xs ----
    {
        const int e0 = wv * 32;
        #pragma unroll
        for (int half = 0; half < 2; ++half)
            #pragma unroll
            for (int z = 0; z < 2; ++z) {
                const int n = half * 64 + z * 32 + l31;
                #pragma unroll
                for (int g = 0; g < 4; ++g)
                    *(bf16x4*)&Xs[(size_t)n * XSTR + e0 + 8 * g + 4 * lh] = hreg[half][z][g];
            }
    }
    __syncthreads();

    // ---- Phase 2: layer 2, f -> hreg ----
    {
        const bf16_t* wbase = wf + 65536 + ((size_t)wv * 16) * 512 + ln * 8;
        f32x16 acc[2][2];
        #pragma unroll
        for (int i = 0; i < 16; ++i) {
            acc[0][0][i] = 0.0f; acc[0][1][i] = 0.0f;
            acc[1][0][i] = 0.0f; acc[1][1][i] = 0.0f;
        }
        #pragma unroll
        for (int kg = 0; kg < 2; ++kg) {
            bf16x8 af[8];
            #pragma unroll
            for (int u = 0; u < 8; ++u)
                af[u] = *(const bf16x8*)(wbase + (size_t)(kg * 8 + u) * 512);
            #pragma unroll
            for (int half = 0; half < 2; ++half) {
                const bf16_t* x0 = Xs + (size_t)(half * 64 + l31) * XSTR + lh * 8;
                const bf16_t* x1 = x0 + 32 * XSTR;
                #pragma unroll
                for (int u = 0; u < 8; ++u) {
                    const int kc = kg * 8 + u;
                    bf16x8 bx0 = *(const bf16x8*)(x0 + kc * 16);
                    bf16x8 bx1 = *(const bf16x8*)(x1 + kc * 16);
                    acc[half][0] = __builtin_amdgcn_mfma_f32_32x32x16_bf16(af[u], bx0, acc[half][0], 0, 0, 0);
                    acc[half][1] = __builtin_amdgcn_mfma_f32_32x32x16_bf16(af[u], bx1, acc[half][1], 0, 0, 0);
                }
            }
        }
        const int e0 = wv * 32;
        #pragma unroll
        for (int half = 0; half < 2; ++half)
            #pragma unroll
            for (int z = 0; z < 2; ++z)
                #pragma unroll
                for (int g = 0; g < 4; ++g) {
                    const int e = e0 + 8 * g + 4 * lh;
                    #pragma unroll
                    for (int rr = 0; rr < 4; ++rr)
                        hreg[half][z][g][rr] = (bf16_t)(acc[half][z][4 * g + rr] + b2_s[e + rr]);
                }
    }
    __syncthreads();             // all waves done reading H

    {
        const int e0 = wv * 32;
        #pragma unroll
        for (int half = 0; half < 2; ++half)
            #pragma unroll
            for (int z = 0; z < 2; ++z) {
                const int n = half * 64 + z * 32 + l31;
                #pragma unroll
                for (int g = 0; g < 4; ++g)
                    *(bf16x4*)&Xs[(size_t)n * XSTR + e0 + 8 * g + 4 * lh] = hreg[half][z][g];
            }
    }
    __syncthreads();             // f now fully in Xs

    // ---- Phase 3: row norms ||f||^2  (512 threads: 4 per row) ----
    {
        const int r = t >> 2;
        const int q = t & 3;
        const bf16_t* frow = &Xs[(size_t)r * XSTR + q * 64];
        float s = 0.0f;
        #pragma unroll
        for (int c = 0; c < 8; ++c) {
            bf16x8 v = *(const bf16x8*)(frow + c * 8);
            #pragma unroll
            for (int u = 0; u < 8; ++u) { float f = (float)v[u]; s = fmaf(f, f, s); }
        }
        s += __shfl_xor(s, 1);
        s += __shfl_xor(s, 2);
        if (q == 0) nrm[r] = s;
    }
    __syncthreads();

    // ---- Phase 4: cdist (waves 0..3), C -> global ----
    if (wv < 4) {
        const int qt = wv >> 1, rt = wv & 1;
        const bf16_t* qa = &Xs[(size_t)(qt * 32 + l31) * XSTR + lh * 8];
        const bf16_t* ra = &Xs[(size_t)(64 + rt * 32 + l31) * XSTR + lh * 8];
        f32x16 acc;
        #pragma unroll
        for (int i = 0; i < 16; ++i) acc[i] = 0.0f;
        #pragma unroll
        for (int kc = 0; kc < 16; ++kc) {
            bf16x8 av = *(const bf16x8*)(qa + kc * 16);
            bf16x8 bv = *(const bf16x8*)(ra + kc * 16);
            acc = __builtin_amdgcn_mfma_f32_32x32x16_bf16(av, bv, acc, 0, 0, 0);
        }
        const int mcol  = rt * 32 + l31;
        const int qbase = qt * 32;
        const float nr_m = nrm[64 + mcol];
        float* outC = out + 2048 + (size_t)2048 * 4096 + (size_t)b * 4096;
        #pragma unroll
        for (int g = 0; g < 4; ++g) {
            #pragma unroll
            for (int rr = 0; rr < 4; ++rr) {
                const int q = qbase + 8 * g + 4 * lh + rr;
                float d2 = nrm[q] + nr_m - 2.0f * acc[4 * g + rr];
                outC[q * 64 + mcol] = sqrtf(fmaxf(d2, 0.0f));
            }
        }
    }
}

// ---------------------------------------------------------------------------
// Kernel B: wave-local Sinkhorn. One WAVE per batch, ZERO barriers.
// Lane k owns row k: rV[64] = -IEPS*C[k][*] + lmr[*] (regs),
//                    cV[64] = -IEPS*C[*][k] + lmq[*] (regs, iter-invariant).
// la/lb live in per-wave LDS arrays; wave-synchronous LDS needs no s_barrier.
// T lives in v[64] regs; power-iter col sums via register shfl_xor butterfly.
// LDS/wave = 64*65*4 (C) + 3*256 = 17.4 KB; 4 waves/block -> 69.6 KB
// -> 2 blocks/CU -> all 2048 batches resident, fully independent.
// ---------------------------------------------------------------------------
__global__ __launch_bounds__(256, 2) void sinkhorn_wave(
    const float* __restrict__ mq, const float* __restrict__ mr,
    float* __restrict__ out) {

    __shared__ float Cw4[4][64 * 65];
    __shared__ float lmr4[4][64];
    __shared__ float la4[4][64];
    __shared__ float lb4[4][64];

    const int t  = threadIdx.x;
    const int ln = t & 63;
    const int wv = t >> 6;
    const int b  = blockIdx.x * 4 + wv;

    float* Cw   = Cw4[wv];
    float* lmrw = lmr4[wv];
    float* law  = la4[wv];
    float* lbw  = lb4[wv];

    const float lmq_k = __logf(fmaxf(mq[(size_t)b * 64 + ln], 1e-8f));
    const float lmr_m = __logf(fmaxf(mr[(size_t)b * 64 + ln], 1e-8f));
    lmrw[ln] = lmr_m;
    law[ln]  = lmq_k;     // temporarily holds lmq for the cV init
    lbw[ln]  = 0.0f;

    // ---- stage C row-major -> LDS (stride 65: conflict-free rows AND cols) ----
    const float* Cg = out + 2048 + (size_t)2048 * 4096 + (size_t)b * 4096;
    #pragma unroll
    for (int i = 0; i < 16; ++i) {
        const int r  = i * 4 + (ln >> 4);
        const int c4 = (ln & 15) * 4;
        const float4 vv = *(const float4*)(Cg + r * 64 + c4);
        float* dst = &Cw[r * 65 + c4];
        dst[0] = vv.x; dst[1] = vv.y; dst[2] = vv.z; dst[3] = vv.w;
    }

    // ---- per-lane row/col caches (wave-sync via lgkmcnt, no barrier) ----
    float rV[64], cV[64], v[64];
    #pragma unroll
    for (int m = 0; m < 64; ++m)
        rV[m] = fmaf(Cw[ln * 65 + m], -IEPS, lmrw[m]);
    #pragma unroll
    for (int j = 0; j < 64; ++j)
        cV[j] = fmaf(Cw[j * 65 + ln], -IEPS, law[j]);

    float la_k = 0.0f;
    for (int it = 0; it < NITER; ++it) {
        // la-update: la[k] = -(lmq[k] + LSE_m(rV[m] + lb[m]))
        {
            float m0 = -1e30f, m1 = -1e30f, m2 = -1e30f, m3 = -1e30f;
            #pragma unroll
            for (int m = 0; m < 64; m += 4) {
                v[m]     = rV[m]     + lbw[m];
                v[m + 1] = rV[m + 1] + lbw[m + 1];
                v[m + 2] = rV[m + 2] + lbw[m + 2];
                v[m + 3] = rV[m + 3] + lbw[m + 3];
                m0 = fmaxf(m0, v[m]);     m1 = fmaxf(m1, v[m + 1]);
                m2 = fmaxf(m2, v[m + 2]); m3 = fmaxf(m3, v[m + 3]);
            }
            const float mx = fmaxf(fmaxf(m0, m1), fmaxf(m2, m3));
            float s0 = 0.0f, s1 = 0.0f, s2 = 0.0f, s3 = 0.0f;
            #pragma unroll
            for (int m = 0; m < 64; m += 4) {
                s0 += __expf(v[m] - mx);     s1 += __expf(v[m + 1] - mx);
                s2 += __expf(v[m + 2] - mx); s3 += __expf(v[m + 3] - mx);
            }
            la_k = -(lmq_k + mx + __logf((s0 + s1) + (s2 + s3)));
            law[ln] = la_k;
        }
        // lb-update: lb[m] = -(lmr[m] + LSE_k(cV[k] + la[k]))
        {
            float m0 = -1e30f, m1 = -1e30f, m2 = -1e30f, m3 = -1e30f;
            #pragma unroll
            for (int j = 0; j < 64; j += 4) {
                v[j]     = cV[j]     + law[j];
                v[j + 1] = cV[j + 1] + law[j + 1];
                v[j + 2] = cV[j + 2] + law[j + 2];
                v[j + 3] = cV[j + 3] + law[j + 3];
                m0 = fmaxf(m0, v[j]);     m1 = fmaxf(m1, v[j + 1]);
                m2 = fmaxf(m2, v[j + 2]); m3 = fmaxf(m3, v[j + 3]);
            }
            const float mx = fmaxf(fmaxf(m0, m1), fmaxf(m2, m3));
            float s0 = 0.0f, s1 = 0.0f, s2 = 0.0f, s3 = 0.0f;
            #pragma unroll
            for (int j = 0; j < 64; j += 4) {
                s0 += __expf(v[j] - mx);     s1 += __expf(v[j + 1] - mx);
                s2 += __expf(v[j + 2] - mx); s3 += __expf(v[j + 3] - mx);
            }
            const float lb_m = -(lmr_m + mx + __logf((s0 + s1) + (s2 + s3)));
            lbw[ln] = lb_m;
        }
    }

    // ---- T = exp(lK + la + lb)  (into v[] regs; rV stays = C info) ----
    {
        const float base = lmq_k + la_k;
        #pragma unroll
        for (int m = 0; m < 64; ++m)
            v[m] = __expf(rV[m] + lbw[m] + base);
    }

    // ---- power iterations (row sums lane-local, col sums via butterfly) ----
    for (int pi = 0; pi < MITER; ++pi) {
        float r0 = 0.0f, r1 = 0.0f, r2 = 0.0f, r3 = 0.0f;
        #pragma unroll
        for (int m = 0; m < 64; m += 4) {
            v[m] *= v[m]; v[m + 1] *= v[m + 1];
            v[m + 2] *= v[m + 2]; v[m + 3] *= v[m + 3];
            r0 += v[m]; r1 += v[m + 1]; r2 += v[m + 2]; r3 += v[m + 3];
        }
        const float rinv = 1.0f / (((r0 + r1) + (r2 + r3)) + 1e-8f);
        #pragma unroll
        for (int m = 0; m < 64; ++m) v[m] *= rinv;

        #pragma unroll
        for (int m = 0; m < 64; ++m) cV[m] = v[m];
        #pragma unroll
        for (int off = 1; off < 64; off <<= 1) {
            #pragma unroll
            for (int m = 0; m < 64; ++m)
                cV[m] += __shfl_xor(cV[m], off);
        }
        #pragma unroll
        for (int m = 0; m < 64; ++m) v[m] *= 1.0f / (cV[m] + 1e-8f);
    }

    // ---- c = sum(T*C) ----
    float d0 = 0.0f, d1 = 0.0f, d2 = 0.0f, d3 = 0.0f;
    #pragma unroll
    for (int m = 0; m < 64; m += 4) {
        d0 = fmaf(v[m],     Cw[ln * 65 + m],     d0);
        d1 = fmaf(v[m + 1], Cw[ln * 65 + m + 1], d1);
        d2 = fmaf(v[m + 2], Cw[ln * 65 + m + 2], d2);
        d3 = fmaf(v[m + 3], Cw[ln * 65 + m + 3], d3);
    }
    float part = (d0 + d1) + (d2 + d3);
    #pragma unroll
    for (int off = 1; off < 64; off <<= 1) part += __shfl_xor(part, off);

    // ---- write T: LDS bounce for coalesced stores (Cw is dead now) ----
    #pragma unroll
    for (int m = 0; m < 64; ++m) Cw[ln * 65 + m] = v[m];
    float* outT = out + 2048 + (size_t)b * 4096;
    #pragma unroll
    for (int r = 0; r < 64; ++r)
        outT[r * 64 + ln] = Cw[r * 65 + ln];

    if (ln == 0) {
        out[2048 + (size_t)2 * 2048 * 4096 + b] = part;
        out[b] = 1.0f / (1.0f + __expf(part));
    }
}

extern "C" void kernel_launch(void* const* d_in, const int* in_sizes, int n_in,
                              void* d_out, int out_size, void* d_ws, size_t ws_size,
                              hipStream_t stream) {
    const float* sq = (const float*)d_in[0];
    const float* sr = (const float*)d_in[1];
    const float* mq = (const float*)d_in[2];
    const float* mr = (const float*)d_in[3];
    const float* W1 = (const float*)d_in[4];
    const float* b1 = (const float*)d_in[5];
    const float* W2 = (const float*)d_in[6];
    const float* b2 = (const float*)d_in[7];

    bf16_t* wf = (bf16_t*)d_ws;   // 131072 bf16 = 256 KB

    convert_w_frag<<<512, 256, 0, stream>>>(W1, W2, wf);
    mlp_cdist<<<NB, 512, 0, stream>>>(sq, sr, b1, b2, wf, (float*)d_out);
    sinkhorn_wave<<<NB / 4, 256, 0, stream>>>(mq, mr, (float*)d_out);
}